// Round 9
// baseline (30819.995 us; speedup 1.0000x reference)
//
#include <hip/hip_runtime.h>
#include <hip/hip_cooperative_groups.h>
#include <math.h>

namespace cg = cooperative_groups;

#define N_NODES 10000
#define N_EDGES 320000
#define TPB 256

// ---------------- edge_index dtype detection ----------------
__global__ void k_detect(const int* __restrict__ ei, int* __restrict__ flag) {
  __shared__ int any_nz;
  if (threadIdx.x == 0) any_nz = 0;
  __syncthreads();
  if (ei[2 * threadIdx.x + 1] != 0) atomicOr(&any_nz, 1);
  __syncthreads();
  if (threadIdx.x == 0) *flag = (any_nz == 0) ? 1 : 0;  // 1 => int64 layout
}

__device__ __forceinline__ int2 load_edge(const int* __restrict__ ei, int e, int is64) {
  if (is64) return make_int2(ei[2 * e], ei[2 * N_EDGES + 2 * e]);
  return make_int2(ei[e], ei[N_EDGES + e]);
}

// ---------------- preprocessing ----------------

__global__ void k_init(float* __restrict__ deg, int* __restrict__ cnt) {
  int i = blockIdx.x * blockDim.x + threadIdx.x;
  if (i < N_NODES) { deg[i] = 0.f; cnt[i] = 0; }
}

__global__ void k_deg(const int* __restrict__ ei, const float* __restrict__ w,
                      const int* __restrict__ flag,
                      float* __restrict__ deg, int* __restrict__ cnt) {
  const int is64 = *flag;
  int e = blockIdx.x * blockDim.x + threadIdx.x;
  if (e < N_EDGES) {
    int2 sd = load_edge(ei, e, is64);
    atomicAdd(&deg[sd.x], w[e]);
    atomicAdd(&cnt[sd.y], 1);
  }
}

__global__ __launch_bounds__(1024) void k_scan(const float* __restrict__ deg,
                                               float* __restrict__ dis,
                                               const int* __restrict__ cnt,
                                               int* __restrict__ row_ptr,
                                               int* __restrict__ cur) {
  __shared__ int sbuf[1024];
  const int tid = threadIdx.x;
  for (int i = tid; i < N_NODES; i += 1024) {
    float d = deg[i];
    dis[i] = d > 0.f ? 1.f / sqrtf(d) : 0.f;
    cur[i] = 0;
  }
  __syncthreads();
  int run = 0;
  for (int base = 0; base < N_NODES; base += 1024) {
    int v = (base + tid < N_NODES) ? cnt[base + tid] : 0;
    sbuf[tid] = v;
    __syncthreads();
    for (int o = 1; o < 1024; o <<= 1) {
      int t = (tid >= o) ? sbuf[tid - o] : 0;
      __syncthreads();
      sbuf[tid] += t;
      __syncthreads();
    }
    if (base + tid < N_NODES) row_ptr[base + tid + 1] = run + sbuf[tid];
    int tot = sbuf[1023];
    __syncthreads();
    run += tot;
  }
  if (tid == 0) row_ptr[0] = 0;
}

__global__ void k_fill(const int* __restrict__ ei, const float* __restrict__ w,
                       const int* __restrict__ flag, const float* __restrict__ dis,
                       const int* __restrict__ row_ptr, int* __restrict__ cur,
                       int2* __restrict__ edat) {
  const int is64 = *flag;
  int e = blockIdx.x * blockDim.x + threadIdx.x;
  if (e < N_EDGES) {
    int2 sd = load_edge(ei, e, is64);
    int p = row_ptr[sd.y] + atomicAdd(&cur[sd.y], 1);
    float v = -dis[sd.x] * w[e] * dis[sd.y];
    edat[p] = make_int2(sd.x, __float_as_int(v));
  }
}

// transpose W (K,CI,CO) -> Wt (K,CO,CI)
__global__ void k_tr(const float* __restrict__ W, float* __restrict__ Wt,
                     int K, int CI, int CO) {
  int i = blockIdx.x * blockDim.x + threadIdx.x;
  int tot = K * CI * CO;
  if (i < tot) {
    int k = i / (CI * CO), r = i % (CI * CO);
    int ci = r / CO, co = r % CO;
    Wt[k * CI * CO + co * CI + ci] = W[i];
  }
}

// ---------------- gather helper (60-channel rows, lane = channel) ----------------
__device__ __forceinline__ float gather60(const int2* __restrict__ edat, int e0, int e1,
                                          const float* __restrict__ t, int cl) {
  float a0 = 0.f, a1 = 0.f, a2 = 0.f, a3 = 0.f, a4 = 0.f, a5 = 0.f, a6 = 0.f, a7 = 0.f;
  int e = e0;
  for (; e + 7 < e1; e += 8) {
    int2 d0 = edat[e],     d1 = edat[e + 1], d2 = edat[e + 2], d3 = edat[e + 3];
    int2 d4 = edat[e + 4], d5 = edat[e + 5], d6 = edat[e + 6], d7 = edat[e + 7];
    a0 += __int_as_float(d0.y) * t[d0.x * 60 + cl];
    a1 += __int_as_float(d1.y) * t[d1.x * 60 + cl];
    a2 += __int_as_float(d2.y) * t[d2.x * 60 + cl];
    a3 += __int_as_float(d3.y) * t[d3.x * 60 + cl];
    a4 += __int_as_float(d4.y) * t[d4.x * 60 + cl];
    a5 += __int_as_float(d5.y) * t[d5.x * 60 + cl];
    a6 += __int_as_float(d6.y) * t[d6.x * 60 + cl];
    a7 += __int_as_float(d7.y) * t[d7.x * 60 + cl];
  }
  for (; e < e1; e++) { int2 d = edat[e]; a0 += __int_as_float(d.y) * t[d.x * 60 + cl]; }
  return ((a0 + a1) + (a2 + a3)) + ((a4 + a5) + (a6 + a7));
}

// ---------------- persistent layer kernels (cooperative), templated on grid ----------------
// NBLK blocks x 4 waves; each wave owns NPW nodes (slot s -> node gw + s*NBLK*4).

// Layer 1: CI=2, CO=60, K=200.
template <int NBLK, int NPW>
__global__ __launch_bounds__(TPB, 2) void k_layer_narrow(
    const int* __restrict__ rowp, const int2* __restrict__ edat,
    const float* __restrict__ x,      // stride 2
    const float* __restrict__ Wt,     // [200][60][2]
    const float* __restrict__ bias,
    float* __restrict__ bufA, float* __restrict__ bufB,  // stride 2
    float* __restrict__ h_out)        // stride 60
{
  constexpr int NW = NBLK * 4;
  cg::grid_group grid = cg::this_grid();
  const int wid = threadIdx.x >> 6, lane = threadIdx.x & 63;
  const int gw = blockIdx.x * 4 + wid;
  const int co = (lane < 60) ? lane : 0;
  int nodes[NPW], starts[NPW], ends[NPW];
  float A0[NPW], A1[NPW], B0[NPW], B1[NPW], acc[NPW];
#pragma unroll
  for (int s = 0; s < NPW; s++) {
    int nd = gw + s * NW; nodes[s] = nd;
    bool v = nd < N_NODES;
    starts[s] = v ? rowp[nd] : 0;
    ends[s]   = v ? rowp[nd + 1] : 0;
  }
#pragma unroll
  for (int s = 0; s < NPW; s++) {
    bool v = nodes[s] < N_NODES;
    float x0 = 0.f, x1 = 0.f;
    if (v) { float2 xv = *reinterpret_cast<const float2*>(x + nodes[s] * 2); x0 = xv.x; x1 = xv.y; }
    float s0 = 0.f, s1 = 0.f;
    for (int e = starts[s] + lane; e < ends[s]; e += 64) {
      int2 d = edat[e]; float w = __int_as_float(d.y);
      float2 tv = *reinterpret_cast<const float2*>(x + d.x * 2);
      s0 += w * tv.x; s1 += w * tv.y;
    }
#pragma unroll
    for (int o = 32; o; o >>= 1) { s0 += __shfl_xor(s0, o); s1 += __shfl_xor(s1, o); }
    A0[s] = x0; A1[s] = x1; B0[s] = s0; B1[s] = s1;
    if (v && lane == 0) *reinterpret_cast<float2*>(bufB + nodes[s] * 2) = make_float2(s0, s1);
    float2 w0 = *reinterpret_cast<const float2*>(Wt + co * 2);
    float2 w1 = *reinterpret_cast<const float2*>(Wt + (60 + co) * 2);
    acc[s] = bias[co] + x0 * w0.x + x1 * w0.y + s0 * w1.x + s1 * w1.y;
  }
  const float* rb = bufB; float* wb = bufA;
  for (int k = 2; k < 200; k++) {
    grid.sync();
    const float2 wk = *reinterpret_cast<const float2*>(Wt + ((size_t)k * 60 + co) * 2);
#pragma unroll
    for (int s = 0; s < NPW; s++) {
      float s0 = 0.f, s1 = 0.f;
      for (int e = starts[s] + lane; e < ends[s]; e += 64) {
        int2 d = edat[e]; float w = __int_as_float(d.y);
        float2 tv = *reinterpret_cast<const float2*>(rb + d.x * 2);
        s0 += w * tv.x; s1 += w * tv.y;
      }
#pragma unroll
      for (int o = 32; o; o >>= 1) { s0 += __shfl_xor(s0, o); s1 += __shfl_xor(s1, o); }
      float t0 = 2.f * s0 - A0[s], t1 = 2.f * s1 - A1[s];
      A0[s] = B0[s]; A1[s] = B1[s]; B0[s] = t0; B1[s] = t1;
      if (nodes[s] < N_NODES && lane == 0)
        *reinterpret_cast<float2*>(wb + nodes[s] * 2) = make_float2(t0, t1);
      acc[s] += t0 * wk.x + t1 * wk.y;
    }
    const float* t = rb; rb = wb; wb = (float*)t;
  }
#pragma unroll
  for (int s = 0; s < NPW; s++)
    if (nodes[s] < N_NODES && lane < 60) {
      float v = acc[s];
      h_out[nodes[s] * 60 + lane] = v / (1.f + expf(-v));  // silu
    }
}

// Layers 2/3: CI=60, CO in {60,30}. FINAL folds h@W4 + sigmoid epilogue.
template <int NBLK, int NPW, int CO, bool FINAL>
__global__ __launch_bounds__(TPB, 2) void k_layer_wide(
    const int* __restrict__ rowp, const int2* __restrict__ edat,
    const float* __restrict__ h_in,   // stride 60
    const float* __restrict__ Wt,     // [K][CO][60]
    const float* __restrict__ bias, int K,
    float* __restrict__ bufA, float* __restrict__ bufB,  // stride 60
    float* __restrict__ h_out,        // !FINAL: stride 60
    const float* __restrict__ W4,     // FINAL only (30,)
    float* __restrict__ out)          // FINAL only
{
  constexpr int NW = NBLK * 4;
  cg::grid_group grid = cg::this_grid();
  __shared__ __align__(16) float ts[4][NPW][64];
  const int wid = threadIdx.x >> 6, lane = threadIdx.x & 63;
  const int gw = blockIdx.x * 4 + wid;
  const int cl = (lane < 60) ? lane : 59;
  const int co = (lane < CO) ? lane : 0;
  int nodes[NPW], starts[NPW], ends[NPW];
  float A[NPW], Bv[NPW], acc[NPW];
#pragma unroll
  for (int s = 0; s < NPW; s++) {
    int nd = gw + s * NW; nodes[s] = nd;
    bool v = nd < N_NODES;
    starts[s] = v ? rowp[nd] : 0;
    ends[s]   = v ? rowp[nd + 1] : 0;
    A[s] = v ? h_in[nd * 60 + cl] : 0.f;                     // T0
    float g = gather60(edat, starts[s], ends[s], h_in, cl);  // T1
    Bv[s] = g;
    if (v && lane < 60) bufB[nd * 60 + lane] = g;
    acc[s] = bias[co];
  }
  // acc += T0 @ W[0] + T1 @ W[1]
#pragma unroll
  for (int s = 0; s < NPW; s++) ts[wid][s][lane] = A[s];
  __builtin_amdgcn_wave_barrier();
  {
    const float* wr = Wt + (size_t)co * 60;
#pragma unroll
    for (int c4 = 0; c4 < 15; c4++) {
      float4 w = *reinterpret_cast<const float4*>(wr + c4 * 4);
#pragma unroll
      for (int s = 0; s < NPW; s++) {
        float4 tv = *reinterpret_cast<const float4*>(&ts[wid][s][c4 * 4]);
        acc[s] += w.x * tv.x + w.y * tv.y + w.z * tv.z + w.w * tv.w;
      }
    }
  }
  __builtin_amdgcn_wave_barrier();
#pragma unroll
  for (int s = 0; s < NPW; s++) ts[wid][s][lane] = Bv[s];
  __builtin_amdgcn_wave_barrier();
  {
    const float* wr = Wt + ((size_t)CO + co) * 60;
#pragma unroll
    for (int c4 = 0; c4 < 15; c4++) {
      float4 w = *reinterpret_cast<const float4*>(wr + c4 * 4);
#pragma unroll
      for (int s = 0; s < NPW; s++) {
        float4 tv = *reinterpret_cast<const float4*>(&ts[wid][s][c4 * 4]);
        acc[s] += w.x * tv.x + w.y * tv.y + w.z * tv.z + w.w * tv.w;
      }
    }
  }
  const float* rb = bufB; float* wb = bufA;
  for (int k = 2; k < K; k++) {
    grid.sync();  // step k-1 writes visible before step k gathers
    __builtin_amdgcn_wave_barrier();
#pragma unroll
    for (int s = 0; s < NPW; s++) {
      float g = gather60(edat, starts[s], ends[s], rb, cl);
      float tn = 2.f * g - A[s];
      A[s] = Bv[s]; Bv[s] = tn;
      if (nodes[s] < N_NODES && lane < 60) wb[nodes[s] * 60 + lane] = tn;
      ts[wid][s][lane] = tn;
    }
    __builtin_amdgcn_wave_barrier();
    const float* wr = Wt + ((size_t)k * CO + co) * 60;
#pragma unroll
    for (int c4 = 0; c4 < 15; c4++) {
      float4 w = *reinterpret_cast<const float4*>(wr + c4 * 4);
#pragma unroll
      for (int s = 0; s < NPW; s++) {
        float4 tv = *reinterpret_cast<const float4*>(&ts[wid][s][c4 * 4]);
        acc[s] += w.x * tv.x + w.y * tv.y + w.z * tv.z + w.w * tv.w;
      }
    }
    const float* t = rb; rb = wb; wb = (float*)t;
  }
  if constexpr (!FINAL) {
#pragma unroll
    for (int s = 0; s < NPW; s++)
      if (nodes[s] < N_NODES && lane < CO) {
        float v = acc[s];
        h_out[nodes[s] * 60 + lane] = v / (1.f + expf(-v));  // silu, stride 60
      }
  } else {
#pragma unroll
    for (int s = 0; s < NPW; s++) {
      float p = 0.f;
      if (lane < 30) { float v = acc[s]; p = (v / (1.f + expf(-v))) * W4[lane]; }
#pragma unroll
      for (int o = 32; o; o >>= 1) p += __shfl_xor(p, o);
      if (lane == 0 && nodes[s] < N_NODES) out[nodes[s]] = 1.f / (1.f + expf(-p));
    }
  }
}

// ---------------- fallback: per-step kernels (verified round-3 path) ----------------

template <int CIN, int COUT, int SIN, bool FIRST, bool LAST>
__global__ __launch_bounds__(256) void k_cheb(
    const int* __restrict__ row_ptr, const int2* __restrict__ edat,
    const float* __restrict__ t_cur, const float* __restrict__ t_prev, int sprev,
    float* __restrict__ t_next,
    const float* __restrict__ Wkt, const float* __restrict__ W0t,
    const float* __restrict__ bias,
    float* __restrict__ acc, float* __restrict__ h_out) {
  constexpr int ST = (CIN == 2) ? 2 : 64;
  constexpr int SCUR = FIRST ? SIN : ST;
  __shared__ __align__(16) float ts[4][(CIN > 4) ? 64 : 1];
  __shared__ __align__(16) float xs[4][(FIRST && CIN > 4) ? 64 : 1];
  const int wid = threadIdx.x >> 6, lane = threadIdx.x & 63;
  const int node = blockIdx.x * 4 + wid;
  const int start = row_ptr[node], end = row_ptr[node + 1];
  float tn0 = 0.f, tn1 = 0.f;

  if constexpr (CIN == 2) {
    float s0 = 0.f, s1 = 0.f;
    for (int e = start + lane; e < end; e += 64) {
      int2 ed = edat[e];
      float wv = __int_as_float(ed.y);
      float2 v = *reinterpret_cast<const float2*>(t_cur + ed.x * SCUR);
      s0 += wv * v.x; s1 += wv * v.y;
    }
#pragma unroll
    for (int o = 32; o; o >>= 1) { s0 += __shfl_xor(s0, o); s1 += __shfl_xor(s1, o); }
    if constexpr (FIRST) { tn0 = s0; tn1 = s1; }
    else {
      tn0 = 2.f * s0 - t_prev[node * sprev];
      tn1 = 2.f * s1 - t_prev[node * sprev + 1];
    }
    if (lane == 0) *reinterpret_cast<float2*>(t_next + node * ST) = make_float2(tn0, tn1);
  } else {
    const int cl = (lane < CIN) ? lane : 0;
    float a0 = 0.f, a1 = 0.f, a2 = 0.f, a3 = 0.f;
    int e = start;
    if (e < end && (e & 1)) {
      int2 ed = edat[e];
      a0 += __int_as_float(ed.y) * t_cur[ed.x * SCUR + cl];
      e++;
    }
    for (; e + 3 < end; e += 4) {
      int4 p0 = *reinterpret_cast<const int4*>(edat + e);
      int4 p1 = *reinterpret_cast<const int4*>(edat + e + 2);
      a0 += __int_as_float(p0.y) * t_cur[p0.x * SCUR + cl];
      a1 += __int_as_float(p0.w) * t_cur[p0.z * SCUR + cl];
      a2 += __int_as_float(p1.y) * t_cur[p1.x * SCUR + cl];
      a3 += __int_as_float(p1.w) * t_cur[p1.z * SCUR + cl];
    }
    for (; e < end; e++) {
      int2 ed = edat[e];
      a0 += __int_as_float(ed.y) * t_cur[ed.x * SCUR + cl];
    }
    float p = (a0 + a1) + (a2 + a3);
    float tn;
    if constexpr (FIRST) tn = p;
    else tn = 2.f * p - t_prev[node * sprev + cl];
    if (lane < CIN) {
      t_next[node * ST + lane] = tn;
      ts[wid][lane] = tn;
      if constexpr (FIRST) xs[wid][lane] = t_cur[node * SIN + lane];
    }
    __builtin_amdgcn_wave_barrier();
  }

  if (lane < COUT) {
    float sum;
    if constexpr (FIRST) sum = bias[lane];
    else sum = acc[node * COUT + lane];
    if constexpr (CIN == 2) {
      const float2 wk = *reinterpret_cast<const float2*>(Wkt + lane * 2);
      sum += tn0 * wk.x + tn1 * wk.y;
      if constexpr (FIRST) {
        const float2 w0 = *reinterpret_cast<const float2*>(W0t + lane * 2);
        float x0 = t_cur[node * SIN], x1 = t_cur[node * SIN + 1];
        sum += x0 * w0.x + x1 * w0.y;
      }
    } else {
      const float4* wrow = reinterpret_cast<const float4*>(Wkt + lane * CIN);
#pragma unroll
      for (int c4 = 0; c4 < CIN / 4; c4++) {
        float4 w = wrow[c4];
        float4 t = *reinterpret_cast<const float4*>(&ts[wid][c4 * 4]);
        sum += w.x * t.x + w.y * t.y + w.z * t.z + w.w * t.w;
      }
      if constexpr (FIRST) {
        const float4* w0row = reinterpret_cast<const float4*>(W0t + lane * CIN);
#pragma unroll
        for (int c4 = 0; c4 < CIN / 4; c4++) {
          float4 w = w0row[c4];
          float4 t = *reinterpret_cast<const float4*>(&xs[wid][c4 * 4]);
          sum += w.x * t.x + w.y * t.y + w.z * t.z + w.w * t.w;
        }
      }
    }
    if constexpr (LAST) {
      h_out[node * 60 + lane] = sum / (1.f + expf(-sum));  // silu, stride 60
    } else {
      acc[node * COUT + lane] = sum;
    }
  }
}

__global__ __launch_bounds__(256) void k_out(const float* __restrict__ h3,
                                             const float* __restrict__ W4,
                                             float* __restrict__ out) {
  const int wid = threadIdx.x >> 6, lane = threadIdx.x & 63;
  const int node = blockIdx.x * 4 + wid;
  float v = (lane < 30) ? h3[node * 60 + lane] * W4[lane] : 0.f;
#pragma unroll
  for (int o = 32; o; o >>= 1) v += __shfl_xor(v, o);
  if (lane == 0) out[node] = 1.f / (1.f + expf(-v));
}

template <int CI, int CO, int SIN>
static void run_layer(const float* h_in, float* h_out, const float* Wt, const float* b, int K,
                      const int* rowp, const int2* edat,
                      float* tA, float* tB, float* tC, float* accb, hipStream_t stream) {
  const int GB = N_NODES / 4;
  constexpr int ST = (CI == 2) ? 2 : 64;
  k_cheb<CI, CO, SIN, true, false><<<GB, 256, 0, stream>>>(
      rowp, edat, h_in, nullptr, 0, tA, Wt + CI * CO, Wt, b, accb, nullptr);
  float* ptrs[3] = {tA, tB, tC};
  for (int k = 2; k < K; k++) {
    const float* prev = (k == 2) ? h_in : ptrs[(k - 3) % 3];
    int sprev = (k == 2) ? SIN : ST;
    const float* cur  = ptrs[(k - 2) % 3];
    float* next       = ptrs[(k - 1) % 3];
    if (k < K - 1)
      k_cheb<CI, CO, SIN, false, false><<<GB, 256, 0, stream>>>(
          rowp, edat, cur, prev, sprev, next, Wt + (size_t)k * CI * CO, nullptr, nullptr,
          accb, nullptr);
    else
      k_cheb<CI, CO, SIN, false, true><<<GB, 256, 0, stream>>>(
          rowp, edat, cur, prev, sprev, next, Wt + (size_t)k * CI * CO, nullptr, nullptr,
          accb, h_out);
  }
}

// ---------------- host ----------------

extern "C" void kernel_launch(void* const* d_in, const int* in_sizes, int n_in,
                              void* d_out, int out_size, void* d_ws, size_t ws_size,
                              hipStream_t stream) {
  const float* x  = (const float*)d_in[0];
  const int*   ei = (const int*)d_in[1];
  const float* ew = (const float*)d_in[2];
  const float* W1 = (const float*)d_in[3];
  const float* b1 = (const float*)d_in[4];
  const float* W2 = (const float*)d_in[5];
  const float* b2 = (const float*)d_in[6];
  const float* W3 = (const float*)d_in[7];
  const float* b3 = (const float*)d_in[8];
  const float* W4 = (const float*)d_in[9];
  float* out = (float*)d_out;

  char* ws = (char*)d_ws;
  size_t off = 0;
  auto alloc = [&](size_t bytes) {
    void* p = ws + off;
    off += (bytes + 255) & ~size_t(255);
    return p;
  };
  float* deg  = (float*)alloc(N_NODES * 4);
  float* dis  = (float*)alloc(N_NODES * 4);
  int*   cnt  = (int*)alloc(N_NODES * 4);
  int*   cur  = (int*)alloc(N_NODES * 4);
  int*   rowp = (int*)alloc((N_NODES + 1) * 4);
  int2*  edat = (int2*)alloc(N_EDGES * 8);
  int*   flag = (int*)alloc(256);
  float* Wt1  = (float*)alloc(200 * 2 * 60 * 4);
  float* Wt2  = (float*)alloc(200 * 60 * 60 * 4);
  float* Wt3  = (float*)alloc(20 * 60 * 30 * 4);
  float* tA   = (float*)alloc(N_NODES * 64 * 4);   // coop bufA / fallback t-buffer
  float* tB   = (float*)alloc(N_NODES * 64 * 4);   // coop bufB / fallback t-buffer
  float* tC   = (float*)alloc(N_NODES * 64 * 4);   // fallback only
  float* accb = (float*)alloc(N_NODES * 60 * 4);   // fallback only
  float* h1   = (float*)alloc(N_NODES * 60 * 4);
  float* h2   = (float*)alloc(N_NODES * 60 * 4);
  float* h3   = (float*)alloc(N_NODES * 60 * 4);

  k_detect<<<1, 256, 0, stream>>>(ei, flag);
  k_init<<<(N_NODES + 255) / 256, 256, 0, stream>>>(deg, cnt);
  k_deg<<<(N_EDGES + 255) / 256, 256, 0, stream>>>(ei, ew, flag, deg, cnt);
  k_scan<<<1, 1024, 0, stream>>>(deg, dis, cnt, rowp, cur);
  k_fill<<<(N_EDGES + 255) / 256, 256, 0, stream>>>(ei, ew, flag, dis, rowp, cur, edat);
  k_tr<<<(200 * 2 * 60 + 255) / 256, 256, 0, stream>>>(W1, Wt1, 200, 2, 60);
  k_tr<<<(200 * 60 * 60 + 255) / 256, 256, 0, stream>>>(W2, Wt2, 200, 60, 60);
  k_tr<<<(20 * 60 * 30 + 255) / 256, 256, 0, stream>>>(W3, Wt3, 20, 60, 30);

  int K2 = 200, K3 = 20;

  // Layer 1: coop tier-1 (512 blk) -> coop tier-2 (256 blk) -> per-step fallback
  {
    void* a[] = {(void*)&rowp, (void*)&edat, (void*)&x, (void*)&Wt1, (void*)&b1,
                 (void*)&tA, (void*)&tB, (void*)&h1};
    hipError_t e = hipLaunchCooperativeKernel(
        reinterpret_cast<void*>(&k_layer_narrow<512, 5>), dim3(512), dim3(TPB), a, 0, stream);
    if (e != hipSuccess)
      e = hipLaunchCooperativeKernel(
          reinterpret_cast<void*>(&k_layer_narrow<256, 10>), dim3(256), dim3(TPB), a, 0, stream);
    if (e != hipSuccess)
      run_layer<2, 60, 2>(x, h1, Wt1, b1, 200, rowp, edat, tA, tB, tC, accb, stream);
  }
  // Layer 2
  {
    void* a[] = {(void*)&rowp, (void*)&edat, (void*)&h1, (void*)&Wt2, (void*)&b2, (void*)&K2,
                 (void*)&tA, (void*)&tB, (void*)&h2, (void*)&W4, (void*)&out};
    hipError_t e = hipLaunchCooperativeKernel(
        reinterpret_cast<void*>(&k_layer_wide<512, 5, 60, false>), dim3(512), dim3(TPB), a, 0, stream);
    if (e != hipSuccess)
      e = hipLaunchCooperativeKernel(
          reinterpret_cast<void*>(&k_layer_wide<256, 10, 60, false>), dim3(256), dim3(TPB), a, 0, stream);
    if (e != hipSuccess)
      run_layer<60, 60, 60>(h1, h2, Wt2, b2, 200, rowp, edat, tA, tB, tC, accb, stream);
  }
  // Layer 3 (+ final projection & sigmoid)
  {
    void* a[] = {(void*)&rowp, (void*)&edat, (void*)&h2, (void*)&Wt3, (void*)&b3, (void*)&K3,
                 (void*)&tA, (void*)&tB, (void*)&h3, (void*)&W4, (void*)&out};
    hipError_t e = hipLaunchCooperativeKernel(
        reinterpret_cast<void*>(&k_layer_wide<512, 5, 30, true>), dim3(512), dim3(TPB), a, 0, stream);
    if (e != hipSuccess)
      e = hipLaunchCooperativeKernel(
          reinterpret_cast<void*>(&k_layer_wide<256, 10, 30, true>), dim3(256), dim3(TPB), a, 0, stream);
    if (e != hipSuccess) {
      run_layer<60, 30, 60>(h2, h3, Wt3, b3, 20, rowp, edat, tA, tB, tC, accb, stream);
      k_out<<<N_NODES / 4, 256, 0, stream>>>(h3, W4, out);
    }
  }
}

// Round 11
// 5431.834 us; speedup vs baseline: 5.6740x; 5.6740x over previous
//
#include <hip/hip_runtime.h>
#include <math.h>

#define N_NODES 10000
#define N_EDGES 320000

// ---------------- edge_index dtype detection ----------------
// Reference builds edge_index as int64. If the harness hands us raw int64,
// every odd 32-bit word is 0 (values in [0,10000)). With int32, odd words are
// random node ids — P(256 consecutive zeros) ~ 0.
__global__ void k_detect(const int* __restrict__ ei, int* __restrict__ flag) {
  __shared__ int any_nz;
  if (threadIdx.x == 0) any_nz = 0;
  __syncthreads();
  if (ei[2 * threadIdx.x + 1] != 0) atomicOr(&any_nz, 1);
  __syncthreads();
  if (threadIdx.x == 0) *flag = (any_nz == 0) ? 1 : 0;  // 1 => int64 layout
}

__device__ __forceinline__ int2 load_edge(const int* __restrict__ ei, int e, int is64) {
  if (is64) return make_int2(ei[2 * e], ei[2 * N_EDGES + 2 * e]);
  return make_int2(ei[e], ei[N_EDGES + e]);
}

// ---------------- preprocessing ----------------

__global__ void k_init(float* __restrict__ deg, int* __restrict__ cnt) {
  int i = blockIdx.x * blockDim.x + threadIdx.x;
  if (i < N_NODES) { deg[i] = 0.f; cnt[i] = 0; }
}

__global__ void k_deg(const int* __restrict__ ei, const float* __restrict__ w,
                      const int* __restrict__ flag,
                      float* __restrict__ deg, int* __restrict__ cnt) {
  const int is64 = *flag;
  int e = blockIdx.x * blockDim.x + threadIdx.x;
  if (e < N_EDGES) {
    int2 sd = load_edge(ei, e, is64);
    atomicAdd(&deg[sd.x], w[e]);   // deg = segment_sum(edge_weight, src)
    atomicAdd(&cnt[sd.y], 1);      // CSR row sizes (by dst)
  }
}

// single-block: dis = deg>0 ? rsqrt(deg) : 0 ; exclusive-scan cnt -> row_ptr ; zero cursors
__global__ __launch_bounds__(1024) void k_scan(const float* __restrict__ deg,
                                               float* __restrict__ dis,
                                               const int* __restrict__ cnt,
                                               int* __restrict__ row_ptr,
                                               int* __restrict__ cur) {
  __shared__ int sbuf[1024];
  const int tid = threadIdx.x;
  for (int i = tid; i < N_NODES; i += 1024) {
    float d = deg[i];
    dis[i] = d > 0.f ? 1.f / sqrtf(d) : 0.f;
    cur[i] = 0;
  }
  __syncthreads();
  int run = 0;
  for (int base = 0; base < N_NODES; base += 1024) {
    int v = (base + tid < N_NODES) ? cnt[base + tid] : 0;
    sbuf[tid] = v;
    __syncthreads();
    for (int o = 1; o < 1024; o <<= 1) {            // Hillis-Steele inclusive scan
      int t = (tid >= o) ? sbuf[tid - o] : 0;
      __syncthreads();
      sbuf[tid] += t;
      __syncthreads();
    }
    if (base + tid < N_NODES) row_ptr[base + tid + 1] = run + sbuf[tid];
    int tot = sbuf[1023];
    __syncthreads();
    run += tot;
  }
  if (tid == 0) row_ptr[0] = 0;
}

__global__ void k_fill(const int* __restrict__ ei, const float* __restrict__ w,
                       const int* __restrict__ flag, const float* __restrict__ dis,
                       const int* __restrict__ row_ptr, int* __restrict__ cur,
                       int* __restrict__ col, float* __restrict__ val) {
  const int is64 = *flag;
  int e = blockIdx.x * blockDim.x + threadIdx.x;
  if (e < N_EDGES) {
    int2 sd = load_edge(ei, e, is64);
    int p = row_ptr[sd.y] + atomicAdd(&cur[sd.y], 1);
    col[p] = sd.x;
    val[p] = -dis[sd.x] * w[e] * dis[sd.y];   // wn for L_hat = -D^-1/2 A D^-1/2
  }
}

// ---------------- fused Chebyshev step ----------------
// One wave per node. Prop: lane=channel gathers sum_e wn*t_cur[src][c] (CSR row, serial
// edge loop, 8x unrolled -> 8 independent gather chains for MLP). Then
// t_next = 2*p - t_prev (or p when FIRST). GEMM: row broadcast via LDS,
// lane=output channel, acc += t_next @ Wk (+ x@W0 + b when FIRST); LAST writes
// silu(acc) to h_out. Narrow (CIN==2) path: lanes over edges + shfl_xor reduce.

template <int CIN, int COUT, bool FIRST, bool LAST>
__global__ __launch_bounds__(256) void k_cheb(
    const int* __restrict__ row_ptr, const int* __restrict__ col, const float* __restrict__ val,
    const float* __restrict__ t_cur,   // layer input when FIRST
    const float* __restrict__ t_prev,  // unused when FIRST
    float* __restrict__ t_next,
    const float* __restrict__ Wk,      // W[k] slice (W[1] when FIRST)
    const float* __restrict__ W0,      // FIRST only
    const float* __restrict__ bias,    // FIRST only
    float* __restrict__ acc,
    float* __restrict__ h_out)         // LAST only
{
  __shared__ float ts[4][(CIN > 4) ? CIN : 1];
  __shared__ float xs[4][(FIRST && CIN > 4) ? CIN : 1];
  const int wid = threadIdx.x >> 6, lane = threadIdx.x & 63;
  const int node = blockIdx.x * 4 + wid;   // 10000 % 4 == 0
  const int start = row_ptr[node], end = row_ptr[node + 1];

  float t0 = 0.f, t1 = 0.f;  // CIN==2 results (all lanes)

  if constexpr (CIN == 2) {
    float s0 = 0.f, s1 = 0.f;
    for (int e = start + lane; e < end; e += 64) {
      int c = col[e]; float wv = val[e];
      float2 v = *reinterpret_cast<const float2*>(t_cur + 2 * c);
      s0 += wv * v.x; s1 += wv * v.y;
    }
#pragma unroll
    for (int o = 32; o; o >>= 1) { s0 += __shfl_xor(s0, o); s1 += __shfl_xor(s1, o); }
    if constexpr (FIRST) { t0 = s0; t1 = s1; }
    else { t0 = 2.f * s0 - t_prev[2 * node]; t1 = 2.f * s1 - t_prev[2 * node + 1]; }
    if (lane < 2) t_next[2 * node + lane] = lane ? t1 : t0;
  } else {
    const int cl = (lane < CIN) ? lane : 0;
    float a0 = 0.f, a1 = 0.f, a2 = 0.f, a3 = 0.f;
    float a4 = 0.f, a5 = 0.f, a6 = 0.f, a7 = 0.f;
    int e = start;
    for (; e + 7 < end; e += 8) {   // 8 independent gather chains in flight
      int c0 = col[e],     c1 = col[e + 1], c2 = col[e + 2], c3 = col[e + 3];
      int c4 = col[e + 4], c5 = col[e + 5], c6 = col[e + 6], c7 = col[e + 7];
      float w0 = val[e],     w1 = val[e + 1], w2 = val[e + 2], w3 = val[e + 3];
      float w4 = val[e + 4], w5 = val[e + 5], w6 = val[e + 6], w7 = val[e + 7];
      a0 += w0 * t_cur[c0 * CIN + cl];
      a1 += w1 * t_cur[c1 * CIN + cl];
      a2 += w2 * t_cur[c2 * CIN + cl];
      a3 += w3 * t_cur[c3 * CIN + cl];
      a4 += w4 * t_cur[c4 * CIN + cl];
      a5 += w5 * t_cur[c5 * CIN + cl];
      a6 += w6 * t_cur[c6 * CIN + cl];
      a7 += w7 * t_cur[c7 * CIN + cl];
    }
    for (; e < end; e++) a0 += val[e] * t_cur[col[e] * CIN + cl];
    float p = ((a0 + a1) + (a2 + a3)) + ((a4 + a5) + (a6 + a7));
    float tn;
    if constexpr (FIRST) tn = p;
    else tn = 2.f * p - t_prev[node * CIN + cl];
    if (lane < CIN) {
      t_next[node * CIN + lane] = tn;
      ts[wid][lane] = tn;
      if constexpr (FIRST) xs[wid][lane] = t_cur[node * CIN + lane];
    }
  }
  __syncthreads();

  if (lane < COUT) {
    float sum;
    if constexpr (FIRST) sum = bias[lane];
    else sum = acc[node * COUT + lane];
    if constexpr (CIN == 2) {
      sum += t0 * Wk[lane] + t1 * Wk[COUT + lane];
      if constexpr (FIRST) {
        float x0 = t_cur[2 * node], x1 = t_cur[2 * node + 1];
        sum += x0 * W0[lane] + x1 * W0[COUT + lane];
      }
    } else {
#pragma unroll
      for (int c = 0; c < CIN; c++) sum += ts[wid][c] * Wk[c * COUT + lane];
      if constexpr (FIRST) {
#pragma unroll
        for (int c = 0; c < CIN; c++) sum += xs[wid][c] * W0[c * COUT + lane];
      }
    }
    if constexpr (LAST) {
      h_out[node * COUT + lane] = sum / (1.f + expf(-sum));  // silu
    } else {
      acc[node * COUT + lane] = sum;
    }
  }
}

// final layer: out = sigmoid(h3 @ W4), W4 is (30,)
__global__ __launch_bounds__(256) void k_out(const float* __restrict__ h3,
                                             const float* __restrict__ W4,
                                             float* __restrict__ out) {
  const int wid = threadIdx.x >> 6, lane = threadIdx.x & 63;
  const int node = blockIdx.x * 4 + wid;
  float v = (lane < 30) ? h3[node * 30 + lane] * W4[lane] : 0.f;
#pragma unroll
  for (int o = 32; o; o >>= 1) v += __shfl_xor(v, o);
  if (lane == 0) out[node] = 1.f / (1.f + expf(-v));
}

// ---------------- host-side layer driver ----------------

template <int CI, int CO>
static void run_layer(const float* h_in, float* h_out, const float* W, const float* b, int K,
                      const int* rowp, const int* col, const float* val,
                      float* tA, float* tB, float* tC, float* accb, hipStream_t stream) {
  const int GB = N_NODES / 4;
  k_cheb<CI, CO, true, false><<<GB, 256, 0, stream>>>(rowp, col, val, h_in, nullptr, tA,
                                                      W + CI * CO, W, b, accb, nullptr);
  float* ptrs[3] = {tA, tB, tC};
  for (int k = 2; k < K; k++) {
    const float* prev = (k == 2) ? h_in : ptrs[(k - 3) % 3];
    const float* cur  = ptrs[(k - 2) % 3];
    float* next       = ptrs[(k - 1) % 3];
    if (k < K - 1)
      k_cheb<CI, CO, false, false><<<GB, 256, 0, stream>>>(rowp, col, val, cur, prev, next,
                                                           W + (size_t)k * CI * CO, nullptr,
                                                           nullptr, accb, nullptr);
    else
      k_cheb<CI, CO, false, true><<<GB, 256, 0, stream>>>(rowp, col, val, cur, prev, next,
                                                          W + (size_t)k * CI * CO, nullptr,
                                                          nullptr, accb, h_out);
  }
}

extern "C" void kernel_launch(void* const* d_in, const int* in_sizes, int n_in,
                              void* d_out, int out_size, void* d_ws, size_t ws_size,
                              hipStream_t stream) {
  const float* x  = (const float*)d_in[0];
  const int*   ei = (const int*)d_in[1];   // (2, E), int32 or raw int64 (detected)
  const float* ew = (const float*)d_in[2];
  const float* W1 = (const float*)d_in[3];
  const float* b1 = (const float*)d_in[4];
  const float* W2 = (const float*)d_in[5];
  const float* b2 = (const float*)d_in[6];
  const float* W3 = (const float*)d_in[7];
  const float* b3 = (const float*)d_in[8];
  const float* W4 = (const float*)d_in[9];
  float* out = (float*)d_out;

  // workspace carve-out (~18 MB total)
  char* ws = (char*)d_ws;
  size_t off = 0;
  auto alloc = [&](size_t bytes) {
    void* p = ws + off;
    off += (bytes + 255) & ~size_t(255);
    return p;
  };
  float* deg  = (float*)alloc(N_NODES * 4);
  float* dis  = (float*)alloc(N_NODES * 4);
  int*   cnt  = (int*)alloc(N_NODES * 4);
  int*   cur  = (int*)alloc(N_NODES * 4);
  int*   rowp = (int*)alloc((N_NODES + 1) * 4);
  int*   col  = (int*)alloc(N_EDGES * 4);
  float* val  = (float*)alloc(N_EDGES * 4);
  int*   flag = (int*)alloc(256);
  float* tA   = (float*)alloc(N_NODES * 60 * 4);
  float* tB   = (float*)alloc(N_NODES * 60 * 4);
  float* tC   = (float*)alloc(N_NODES * 60 * 4);
  float* accb = (float*)alloc(N_NODES * 60 * 4);
  float* h1   = (float*)alloc(N_NODES * 60 * 4);
  float* h2   = (float*)alloc(N_NODES * 60 * 4);
  float* h3   = (float*)alloc(N_NODES * 30 * 4);

  // build normalized-Laplacian CSR (by dst) each call (ws is re-poisoned)
  k_detect<<<1, 256, 0, stream>>>(ei, flag);
  k_init<<<(N_NODES + 255) / 256, 256, 0, stream>>>(deg, cnt);
  k_deg<<<(N_EDGES + 255) / 256, 256, 0, stream>>>(ei, ew, flag, deg, cnt);
  k_scan<<<1, 1024, 0, stream>>>(deg, dis, cnt, rowp, cur);
  k_fill<<<(N_EDGES + 255) / 256, 256, 0, stream>>>(ei, ew, flag, dis, rowp, cur, col, val);

  run_layer<2, 60>(x, h1, W1, b1, 200, rowp, col, val, tA, tB, tC, accb, stream);
  run_layer<60, 60>(h1, h2, W2, b2, 200, rowp, col, val, tA, tB, tC, accb, stream);
  run_layer<60, 30>(h2, h3, W3, b3, 20, rowp, col, val, tA, tB, tC, accb, stream);
  k_out<<<N_NODES / 4, 256, 0, stream>>>(h3, W4, out);
}